// Round 1
// baseline (645.488 us; speedup 1.0000x reference)
//
#include <hip/hip_runtime.h>
#include <cstddef>
#include <cstdint>

// GCN 2-layer: (GCNConv -> BN(train) -> PReLU) x2 on N=100000 nodes, F=128, E=800000 edges.
// Pipeline per call (graph-capture safe, all on `stream`):
//   memset cnt/fill/stats -> count deg -> scan -> fill CSR -> dis=rsqrt(deg)
//   gemm1 (x@W1^T -> d_out) -> agg1 (d_out -> bufA, +b1) -> bnstats/params -> bnact (in place)
//   gemm2 (bufA@W2^T -> d_out) -> agg2 (d_out -> bufA, +b2) -> bnstats/params -> bnact (bufA -> d_out)

#define EPS_BN 1e-5f

static __device__ __forceinline__ float4 ld4(const float* p) {
    return *reinterpret_cast<const float4*>(p);
}

// ---------------- degree count ----------------
__global__ __launch_bounds__(256) void k_count(const int* __restrict__ dst, int* __restrict__ cnt, int E) {
    int e = blockIdx.x * 256 + threadIdx.x;
    if (e < E) atomicAdd(&cnt[dst[e]], 1);
}

// ---------------- scan (3 kernels), CHUNK=1024/block ----------------
__global__ __launch_bounds__(256) void k_scanA(const int* __restrict__ cnt, int* __restrict__ partial, int n) {
    __shared__ int sd[256];
    int tid = threadIdx.x;
    int base = blockIdx.x * 1024 + tid * 4;
    int s = 0;
#pragma unroll
    for (int j = 0; j < 4; j++) { int idx = base + j; if (idx < n) s += cnt[idx]; }
    sd[tid] = s; __syncthreads();
    for (int off = 128; off > 0; off >>= 1) {
        if (tid < off) sd[tid] += sd[tid + off];
        __syncthreads();
    }
    if (tid == 0) partial[blockIdx.x] = sd[0];
}

__global__ __launch_bounds__(128) void k_scanB(int* partial, int nb) {
    __shared__ int sd[128];
    int t = threadIdx.x;
    sd[t] = (t < nb) ? partial[t] : 0;
    __syncthreads();
    for (int off = 1; off < 128; off <<= 1) {
        int v = (t >= off) ? sd[t - off] : 0;
        __syncthreads();
        sd[t] += v;
        __syncthreads();
    }
    if (t < nb) partial[t] = (t == 0) ? 0 : sd[t - 1];
}

__global__ __launch_bounds__(256) void k_scanC(const int* __restrict__ cnt, const int* __restrict__ partial,
                                               int* __restrict__ rowptr, int n) {
    __shared__ int sd[256];
    int tid = threadIdx.x;
    int base = blockIdx.x * 1024 + tid * 4;
    int v[4]; int s = 0;
#pragma unroll
    for (int j = 0; j < 4; j++) { int idx = base + j; v[j] = (idx < n) ? cnt[idx] : 0; s += v[j]; }
    sd[tid] = s; __syncthreads();
    for (int off = 1; off < 256; off <<= 1) {
        int u = (tid >= off) ? sd[tid - off] : 0;
        __syncthreads();
        sd[tid] += u;
        __syncthreads();
    }
    int excl = partial[blockIdx.x] + ((tid == 0) ? 0 : sd[tid - 1]);
#pragma unroll
    for (int j = 0; j < 4; j++) { int idx = base + j; if (idx < n) rowptr[idx] = excl; excl += v[j]; }
}

// ---------------- dis = rsqrt(deg), deg = cnt + 1 (self loop) ----------------
__global__ __launch_bounds__(256) void k_dis(const int* __restrict__ cnt, float* __restrict__ dis, int n) {
    int i = blockIdx.x * 256 + threadIdx.x;
    if (i < n) dis[i] = rsqrtf((float)(cnt[i] + 1));
}

// ---------------- CSR fill ----------------
__global__ __launch_bounds__(256) void k_fill(const int* __restrict__ src, const int* __restrict__ dst,
                                              const int* __restrict__ rowptr, int* __restrict__ fillc,
                                              int* __restrict__ colw, int E) {
    int e = blockIdx.x * 256 + threadIdx.x;
    if (e < E) {
        int d = dst[e];
        int pos = rowptr[d] + atomicAdd(&fillc[d], 1);
        colw[pos] = src[e];
    }
}

// ---------------- fp32 GEMM: Y[r][o] = sum_k X[r][k] * W[o][k]  (X:[n,128], W:[128,128]) ----------------
// Block: 256 threads, 64 rows x 128 cols per block; thread: 8 rows x 4 cols.
// W staged in LDS transposed (Ws[k][o], pitch 132 for float4 alignment), in two K-halves of 64.
#define WPITCH 132
__global__ __launch_bounds__(256) void k_gemm(const float* __restrict__ X, const float* __restrict__ W,
                                              float* __restrict__ Y, int n) {
    __shared__ float Ws[64 * WPITCH];
    int tid = threadIdx.x;
    int cg = tid & 31;   // col group: cols 4*cg..4*cg+3
    int rs = tid >> 5;   // row slot 0..7
    int rowBase = blockIdx.x * 64 + rs * 8;
    const float* xr[8];
#pragma unroll
    for (int i = 0; i < 8; i++) {
        int r = rowBase + i; if (r > n - 1) r = n - 1;
        xr[i] = X + (size_t)r * 128;
    }
    float4 acc[8];
#pragma unroll
    for (int i = 0; i < 8; i++) acc[i] = make_float4(0.f, 0.f, 0.f, 0.f);

    int ko = tid & 63, oq = tid >> 6;
    for (int kh = 0; kh < 2; ++kh) {
        __syncthreads();
#pragma unroll
        for (int oo = 0; oo < 128; oo += 4) {
            int o = oo + oq;
            Ws[ko * WPITCH + o] = W[o * 128 + kh * 64 + ko];
        }
        __syncthreads();
#pragma unroll
        for (int k4 = 0; k4 < 16; k4++) {
            int kg = kh * 64 + 4 * k4;
            float4 w0 = ld4(&Ws[(4 * k4 + 0) * WPITCH + 4 * cg]);
            float4 w1 = ld4(&Ws[(4 * k4 + 1) * WPITCH + 4 * cg]);
            float4 w2 = ld4(&Ws[(4 * k4 + 2) * WPITCH + 4 * cg]);
            float4 w3 = ld4(&Ws[(4 * k4 + 3) * WPITCH + 4 * cg]);
#pragma unroll
            for (int i = 0; i < 8; i++) {
                float4 xv = ld4(xr[i] + kg);
                acc[i].x += xv.x * w0.x; acc[i].y += xv.x * w0.y; acc[i].z += xv.x * w0.z; acc[i].w += xv.x * w0.w;
                acc[i].x += xv.y * w1.x; acc[i].y += xv.y * w1.y; acc[i].z += xv.y * w1.z; acc[i].w += xv.y * w1.w;
                acc[i].x += xv.z * w2.x; acc[i].y += xv.z * w2.y; acc[i].z += xv.z * w2.z; acc[i].w += xv.z * w2.w;
                acc[i].x += xv.w * w3.x; acc[i].y += xv.w * w3.y; acc[i].z += xv.w * w3.z; acc[i].w += xv.w * w3.w;
            }
        }
    }
#pragma unroll
    for (int i = 0; i < 8; i++) {
        int r = rowBase + i;
        if (r < n) *reinterpret_cast<float4*>(&Y[(size_t)r * 128 + 4 * cg]) = acc[i];
    }
}

// ---------------- aggregation: out[n] = dis[n]*(sum_e dis[src]*h[src] + dis[n]*h[n]) + b ----------------
// 32 lanes per node (4 feats each, float4), 8 nodes per block.
__global__ __launch_bounds__(256) void k_agg(const float* __restrict__ H, const int* __restrict__ rowptr,
                                             const int* __restrict__ cnt, const int* __restrict__ colw,
                                             const float* __restrict__ dis, const float* __restrict__ bias,
                                             float* __restrict__ out, int n) {
    int lane = threadIdx.x & 31;
    int node = blockIdx.x * 8 + (threadIdx.x >> 5);
    if (node >= n) return;
    float dn = dis[node];
    float4 acc = ld4(&H[(size_t)node * 128 + 4 * lane]);
    acc.x *= dn; acc.y *= dn; acc.z *= dn; acc.w *= dn;   // self loop: dn^2 * h[n] after final *dn
    int beg = rowptr[node];
    int num = cnt[node];
    for (int e = 0; e < num; ++e) {
        int s = colw[beg + e];
        float w = dis[s];
        float4 hv = ld4(&H[(size_t)s * 128 + 4 * lane]);
        acc.x += w * hv.x; acc.y += w * hv.y; acc.z += w * hv.z; acc.w += w * hv.w;
    }
    float4 b = ld4(&bias[4 * lane]);
    acc.x = fmaf(dn, acc.x, b.x);
    acc.y = fmaf(dn, acc.y, b.y);
    acc.z = fmaf(dn, acc.z, b.z);
    acc.w = fmaf(dn, acc.w, b.w);
    *reinterpret_cast<float4*>(&out[(size_t)node * 128 + 4 * lane]) = acc;
}

// ---------------- BN stats: per-feature sum / sumsq ----------------
__global__ __launch_bounds__(128) void k_bnstats(const float* __restrict__ X, float* __restrict__ st, int n) {
    int f = threadIdx.x;
    float s = 0.f, q = 0.f;
    for (int r = blockIdx.x; r < n; r += gridDim.x) {
        float v = X[(size_t)r * 128 + f];
        s += v; q = fmaf(v, v, q);
    }
    atomicAdd(&st[f], s);
    atomicAdd(&st[128 + f], q);
}

__global__ __launch_bounds__(128) void k_bnparams(const float* __restrict__ st, const float* __restrict__ g,
                                                  const float* __restrict__ be, float* __restrict__ sc,
                                                  float* __restrict__ sh, float invN) {
    int f = threadIdx.x;
    float mean = st[f] * invN;
    float var = st[128 + f] * invN - mean * mean;
    float rstd = rsqrtf(var + EPS_BN);
    float scale = g[f] * rstd;
    sc[f] = scale;
    sh[f] = fmaf(-mean, scale, be[f]);
}

// ---------------- fused BN apply + PReLU ----------------
__global__ __launch_bounds__(256) void k_bnact(const float* __restrict__ X, float* __restrict__ Y,
                                               const float* __restrict__ sc, const float* __restrict__ sh,
                                               const float* __restrict__ ap, int total4) {
    int i = blockIdx.x * 256 + threadIdx.x;
    if (i >= total4) return;
    float a = ap[0];
    int f4 = i & 31;
    float4 v = reinterpret_cast<const float4*>(X)[i];
    float4 s = reinterpret_cast<const float4*>(sc)[f4];
    float4 t = reinterpret_cast<const float4*>(sh)[f4];
    v.x = fmaf(v.x, s.x, t.x);
    v.y = fmaf(v.y, s.y, t.y);
    v.z = fmaf(v.z, s.z, t.z);
    v.w = fmaf(v.w, s.w, t.w);
    v.x = v.x > 0.f ? v.x : a * v.x;
    v.y = v.y > 0.f ? v.y : a * v.y;
    v.z = v.z > 0.f ? v.z : a * v.z;
    v.w = v.w > 0.f ? v.w : a * v.w;
    reinterpret_cast<float4*>(Y)[i] = v;
}

extern "C" void kernel_launch(void* const* d_in, const int* in_sizes, int n_in,
                              void* d_out, int out_size, void* d_ws, size_t ws_size,
                              hipStream_t stream) {
    (void)n_in; (void)out_size; (void)ws_size;
    const float* x   = (const float*)d_in[0];
    const int*   ei  = (const int*)d_in[1];
    const float* W1  = (const float*)d_in[2];
    const float* b1  = (const float*)d_in[3];
    const float* g1  = (const float*)d_in[4];
    const float* be1 = (const float*)d_in[5];
    const float* W2  = (const float*)d_in[6];
    const float* b2  = (const float*)d_in[7];
    const float* g2  = (const float*)d_in[8];
    const float* be2 = (const float*)d_in[9];
    const float* ap  = (const float*)d_in[10];
    float* out = (float*)d_out;

    const int N = in_sizes[0] / 128;
    const int E = in_sizes[1] / 2;
    const int* srcIdx = ei;        // edge_index[0]
    const int* dstIdx = ei + E;    // edge_index[1]

    // ---- workspace layout ----
    char* w = (char*)d_ws;
    size_t off = 0;
    auto alloc = [&](size_t bytes) { char* p = w + off; off += (bytes + 255) & ~(size_t)255; return p; };
    int*   cnt     = (int*)  alloc((size_t)N * 4);
    int*   fillc   = (int*)  alloc((size_t)N * 4);
    int*   rowptr  = (int*)  alloc((size_t)N * 4);
    int*   colw    = (int*)  alloc((size_t)E * 4);
    float* dis     = (float*)alloc((size_t)N * 4);
    int*   partial = (int*)  alloc(4096);
    float* stats1  = (float*)alloc(1024);   // sum[128], sumsq[128]
    float* stats2  = (float*)alloc(1024);
    float* sc1     = (float*)alloc(512);
    float* sh1     = (float*)alloc(512);
    float* sc2     = (float*)alloc(512);
    float* sh2     = (float*)alloc(512);
    float* bufA    = (float*)alloc((size_t)N * 128 * 4);

    const float invN = 1.0f / (float)N;
    const int NB = (N + 1023) / 1024;          // scan blocks (<=128 for N<=131072)
    const int gE = (E + 255) / 256;
    const int gN = (N + 255) / 256;
    const int total4 = N * 32;                 // float4 groups

    // zero counters + stats (ws is poisoned 0xAA every call)
    hipMemsetAsync(cnt, 0, (size_t)N * 4, stream);
    hipMemsetAsync(fillc, 0, (size_t)N * 4, stream);
    hipMemsetAsync(stats1, 0, 1024, stream);
    hipMemsetAsync(stats2, 0, 1024, stream);

    // degree + CSR
    k_count<<<gE, 256, 0, stream>>>(dstIdx, cnt, E);
    k_scanA<<<NB, 256, 0, stream>>>(cnt, partial, N);
    k_scanB<<<1, 128, 0, stream>>>(partial, NB);
    k_scanC<<<NB, 256, 0, stream>>>(cnt, partial, rowptr, N);
    k_dis<<<gN, 256, 0, stream>>>(cnt, dis, N);
    k_fill<<<gE, 256, 0, stream>>>(srcIdx, dstIdx, rowptr, fillc, colw, E);

    // ---- layer 1 ----
    k_gemm<<<(N + 63) / 64, 256, 0, stream>>>(x, W1, out, N);                      // h1 -> d_out (scratch)
    k_agg<<<(N + 7) / 8, 256, 0, stream>>>(out, rowptr, cnt, colw, dis, b1, bufA, N);
    k_bnstats<<<512, 128, 0, stream>>>(bufA, stats1, N);
    k_bnparams<<<1, 128, 0, stream>>>(stats1, g1, be1, sc1, sh1, invN);
    k_bnact<<<(total4 + 255) / 256, 256, 0, stream>>>(bufA, bufA, sc1, sh1, ap, total4);

    // ---- layer 2 ----
    k_gemm<<<(N + 63) / 64, 256, 0, stream>>>(bufA, W2, out, N);                   // h2 -> d_out (scratch)
    k_agg<<<(N + 7) / 8, 256, 0, stream>>>(out, rowptr, cnt, colw, dis, b2, bufA, N);
    k_bnstats<<<512, 128, 0, stream>>>(bufA, stats2, N);
    k_bnparams<<<1, 128, 0, stream>>>(stats2, g2, be2, sc2, sh2, invN);
    k_bnact<<<(total4 + 255) / 256, 256, 0, stream>>>(bufA, out, sc2, sh2, ap, total4);
}

// Round 3
// 469.355 us; speedup vs baseline: 1.3753x; 1.3753x over previous
//
#include <hip/hip_runtime.h>
#include <cstddef>
#include <cstdint>

// GCN 2-layer (GCNConv -> BN(train) -> PReLU) x2, N=100000, F=128, E=800000.
// R3: fix R2's B-tile stride bug (512 shorts per 16x32 bf16 tile, not 1024).
// bf16 MFMA GEMM (16x16x32), bf16 inter-op buffers (halves gather bytes).

#define EPS_BN 1e-5f

typedef short short8 __attribute__((ext_vector_type(8)));
typedef float f32x4 __attribute__((ext_vector_type(4)));

static __device__ __forceinline__ unsigned short f2b(float f) {
    union { float f; uint32_t u; } v; v.f = f;
    uint32_t u = v.u;
    return (unsigned short)((u + 0x7FFFu + ((u >> 16) & 1u)) >> 16);
}
static __device__ __forceinline__ float b2f(unsigned short h) {
    union { uint32_t u; float f; } v; v.u = ((uint32_t)h) << 16;
    return v.f;
}
static __device__ __forceinline__ float b2f_s(short h) { return b2f((unsigned short)h); }

// ---------------- degree count ----------------
__global__ __launch_bounds__(256) void k_count(const int* __restrict__ dst, int* __restrict__ cnt, int E) {
    int e = blockIdx.x * 256 + threadIdx.x;
    if (e < E) atomicAdd(&cnt[dst[e]], 1);
}

// ---------------- scan (3 kernels), 1024 elems/block ----------------
__global__ __launch_bounds__(256) void k_scanA(const int* __restrict__ cnt, int* __restrict__ partial, int n) {
    __shared__ int sd[256];
    int tid = threadIdx.x;
    int base = blockIdx.x * 1024 + tid * 4;
    int s = 0;
#pragma unroll
    for (int j = 0; j < 4; j++) { int idx = base + j; if (idx < n) s += cnt[idx]; }
    sd[tid] = s; __syncthreads();
    for (int off = 128; off > 0; off >>= 1) {
        if (tid < off) sd[tid] += sd[tid + off];
        __syncthreads();
    }
    if (tid == 0) partial[blockIdx.x] = sd[0];
}

__global__ __launch_bounds__(128) void k_scanB(int* partial, int nb) {
    __shared__ int sd[128];
    int t = threadIdx.x;
    sd[t] = (t < nb) ? partial[t] : 0;
    __syncthreads();
    for (int off = 1; off < 128; off <<= 1) {
        int v = (t >= off) ? sd[t - off] : 0;
        __syncthreads();
        sd[t] += v;
        __syncthreads();
    }
    if (t < nb) partial[t] = (t == 0) ? 0 : sd[t - 1];
}

__global__ __launch_bounds__(256) void k_scanC(const int* __restrict__ cnt, const int* __restrict__ partial,
                                               int* __restrict__ rowptr, int n) {
    __shared__ int sd[256];
    int tid = threadIdx.x;
    int base = blockIdx.x * 1024 + tid * 4;
    int v[4]; int s = 0;
#pragma unroll
    for (int j = 0; j < 4; j++) { int idx = base + j; v[j] = (idx < n) ? cnt[idx] : 0; s += v[j]; }
    sd[tid] = s; __syncthreads();
    for (int off = 1; off < 256; off <<= 1) {
        int u = (tid >= off) ? sd[tid - off] : 0;
        __syncthreads();
        sd[tid] += u;
        __syncthreads();
    }
    int excl = partial[blockIdx.x] + ((tid == 0) ? 0 : sd[tid - 1]);
#pragma unroll
    for (int j = 0; j < 4; j++) { int idx = base + j; if (idx < n) rowptr[idx] = excl; excl += v[j]; }
}

// ---------------- dis = rsqrt(deg), deg = cnt + 1 (self loop) ----------------
__global__ __launch_bounds__(256) void k_dis(const int* __restrict__ cnt, float* __restrict__ dis, int n) {
    int i = blockIdx.x * 256 + threadIdx.x;
    if (i < n) dis[i] = rsqrtf((float)(cnt[i] + 1));
}

// ---------------- CSR fill ----------------
__global__ __launch_bounds__(256) void k_fill(const int* __restrict__ src, const int* __restrict__ dst,
                                              const int* __restrict__ rowptr, int* __restrict__ fillc,
                                              int* __restrict__ colw, int E) {
    int e = blockIdx.x * 256 + threadIdx.x;
    if (e < E) {
        int d = dst[e];
        int pos = rowptr[d] + atomicAdd(&fillc[d], 1);
        colw[pos] = src[e];
    }
}

// ---------------- cast fp32 -> bf16 (float4 -> ushort4) ----------------
__global__ __launch_bounds__(256) void k_cast(const float* __restrict__ X, unsigned short* __restrict__ Xb, int n4) {
    int i = blockIdx.x * 256 + threadIdx.x;
    if (i >= n4) return;
    float4 v = reinterpret_cast<const float4*>(X)[i];
    ushort4 o;
    o.x = f2b(v.x); o.y = f2b(v.y); o.z = f2b(v.z); o.w = f2b(v.w);
    reinterpret_cast<ushort4*>(Xb)[i] = o;
}

// ---------------- W swizzle: W[o][k] fp32 -> bf16 MFMA B-frag order ----------------
// tile = ct*4+ks (16x32 bf16 = 512 shorts); lane = q*16+nn holds elems j=0..7
//   where o = ct*16+nn, k = ks*32 + q*8 + j.
__global__ __launch_bounds__(256) void k_wprep(const float* __restrict__ W, unsigned short* __restrict__ Wz) {
    int idx = blockIdx.x * 256 + threadIdx.x;   // 0..16383
    int o = idx >> 7, k = idx & 127;
    int ct = o >> 4, nn = o & 15, ks = k >> 5, q = (k >> 3) & 3, j = k & 7;
    Wz[(ct * 4 + ks) * 512 + (q * 16 + nn) * 8 + j] = f2b(W[idx]);
}

// ---------------- MFMA GEMM: Yb[r][o] = sum_k Xb[r][k] * W[o][k], bf16 in/out ----------------
// Block = 4 waves, 64 rows x 128 cols. Wave: 16 rows x 128 cols (8 col-tiles x 4 k-steps).
__global__ __launch_bounds__(256) void k_gemm_mfma(const unsigned short* __restrict__ Xb,
                                                   const unsigned short* __restrict__ Wz,
                                                   unsigned short* __restrict__ Yb, int n) {
    __shared__ unsigned short lds[16384];   // 32 KB = 32 tiles x 512 shorts
    int tid = threadIdx.x;
    const short8* wsrc = (const short8*)Wz;
    short8* ldst = (short8*)lds;
#pragma unroll
    for (int i = 0; i < 8; i++) ldst[tid + 256 * i] = wsrc[tid + 256 * i];
    __syncthreads();

    int wave = tid >> 6, lane = tid & 63;
    int r0 = blockIdx.x * 64 + wave * 16;
    int mrow = lane & 15, quad = lane >> 4;
    int arow = r0 + mrow; if (arow > n - 1) arow = n - 1;
    const short8* aptr = (const short8*)(Xb + (size_t)arow * 128);

    f32x4 acc[8];
#pragma unroll
    for (int ct = 0; ct < 8; ct++) acc[ct] = (f32x4){0.f, 0.f, 0.f, 0.f};

#pragma unroll
    for (int ks = 0; ks < 4; ks++) {
        short8 a = aptr[ks * 4 + quad];   // 16B: X[arow][ks*32 + quad*8 .. +8]
#pragma unroll
        for (int ct = 0; ct < 8; ct++) {
            short8 b = *(const short8*)(lds + (ct * 4 + ks) * 512 + lane * 8);
            acc[ct] = __builtin_amdgcn_mfma_f32_16x16x32_bf16(a, b, acc[ct], 0, 0, 0);
        }
    }
    // C layout: col = lane&15, row = quad*4 + i
#pragma unroll
    for (int i = 0; i < 4; i++) {
        int row = r0 + quad * 4 + i;
        if (row < n) {
#pragma unroll
            for (int ct = 0; ct < 8; ct++)
                Yb[(size_t)row * 128 + ct * 16 + mrow] = f2b(acc[ct][i]);
        }
    }
}

// ---------------- aggregation (bf16 H): out = dn*(sum dis[s]*H[s] + dn*H[n]) + b, store bf16 ----------------
// 16 lanes per node (8 feats each, 16B loads), 16 nodes per block.
__global__ __launch_bounds__(256) void k_agg(const unsigned short* __restrict__ Hb,
                                             const int* __restrict__ rowptr, const int* __restrict__ cnt,
                                             const int* __restrict__ colw, const float* __restrict__ dis,
                                             const float* __restrict__ bias,
                                             unsigned short* __restrict__ outb, int n) {
    int lane = threadIdx.x & 15;
    int node = blockIdx.x * 16 + (threadIdx.x >> 4);
    if (node >= n) return;
    float dn = dis[node];
    short8 hv = *(const short8*)(Hb + (size_t)node * 128 + lane * 8);
    float acc[8];
#pragma unroll
    for (int j = 0; j < 8; j++) acc[j] = dn * b2f_s(hv[j]);
    int beg = rowptr[node];
    int num = cnt[node];
    for (int e = 0; e < num; ++e) {
        int s = colw[beg + e];
        float w = dis[s];
        short8 nb = *(const short8*)(Hb + (size_t)s * 128 + lane * 8);
#pragma unroll
        for (int j = 0; j < 8; j++) acc[j] = fmaf(w, b2f_s(nb[j]), acc[j]);
    }
    const float4 bv0 = reinterpret_cast<const float4*>(bias)[lane * 2 + 0];
    const float4 bv1 = reinterpret_cast<const float4*>(bias)[lane * 2 + 1];
    float bb[8] = {bv0.x, bv0.y, bv0.z, bv0.w, bv1.x, bv1.y, bv1.z, bv1.w};
    short8 ov;
#pragma unroll
    for (int j = 0; j < 8; j++) ov[j] = (short)f2b(fmaf(dn, acc[j], bb[j]));
    *(short8*)(outb + (size_t)node * 128 + lane * 8) = ov;
}

// ---------------- BN stats over bf16 input ----------------
__global__ __launch_bounds__(128) void k_bnstats(const unsigned short* __restrict__ X, float* __restrict__ st, int n) {
    int f = threadIdx.x;
    float s = 0.f, q = 0.f;
    for (int r = blockIdx.x; r < n; r += gridDim.x) {
        float v = b2f(X[(size_t)r * 128 + f]);
        s += v; q = fmaf(v, v, q);
    }
    atomicAdd(&st[f], s);
    atomicAdd(&st[128 + f], q);
}

__global__ __launch_bounds__(128) void k_bnparams(const float* __restrict__ st, const float* __restrict__ g,
                                                  const float* __restrict__ be, float* __restrict__ sc,
                                                  float* __restrict__ sh, float invN) {
    int f = threadIdx.x;
    float mean = st[f] * invN;
    float var = st[128 + f] * invN - mean * mean;
    float rstd = rsqrtf(var + EPS_BN);
    float scale = g[f] * rstd;
    sc[f] = scale;
    sh[f] = fmaf(-mean, scale, be[f]);
}

// ---------------- BN apply + PReLU: bf16 in -> bf16 out ----------------
__global__ __launch_bounds__(256) void k_bnact_b(const unsigned short* __restrict__ X, unsigned short* __restrict__ Y,
                                                 const float* __restrict__ sc, const float* __restrict__ sh,
                                                 const float* __restrict__ ap, int n8) {
    int i = blockIdx.x * 256 + threadIdx.x;
    if (i >= n8) return;
    float a = ap[0];
    int g = i & 15;   // col group: cols g*8..g*8+7
    const float4 s0 = reinterpret_cast<const float4*>(sc)[g * 2 + 0];
    const float4 s1 = reinterpret_cast<const float4*>(sc)[g * 2 + 1];
    const float4 t0 = reinterpret_cast<const float4*>(sh)[g * 2 + 0];
    const float4 t1 = reinterpret_cast<const float4*>(sh)[g * 2 + 1];
    float ss[8] = {s0.x, s0.y, s0.z, s0.w, s1.x, s1.y, s1.z, s1.w};
    float tt[8] = {t0.x, t0.y, t0.z, t0.w, t1.x, t1.y, t1.z, t1.w};
    short8 v = reinterpret_cast<const short8*>(X)[i];
    short8 o;
#pragma unroll
    for (int j = 0; j < 8; j++) {
        float x = fmaf(b2f_s(v[j]), ss[j], tt[j]);
        x = x > 0.f ? x : a * x;
        o[j] = (short)f2b(x);
    }
    reinterpret_cast<short8*>(Y)[i] = o;
}

// ---------------- BN apply + PReLU: bf16 in -> fp32 out ----------------
__global__ __launch_bounds__(256) void k_bnact_f(const unsigned short* __restrict__ X, float* __restrict__ Y,
                                                 const float* __restrict__ sc, const float* __restrict__ sh,
                                                 const float* __restrict__ ap, int n8) {
    int i = blockIdx.x * 256 + threadIdx.x;
    if (i >= n8) return;
    float a = ap[0];
    int g = i & 15;
    const float4 s0 = reinterpret_cast<const float4*>(sc)[g * 2 + 0];
    const float4 s1 = reinterpret_cast<const float4*>(sc)[g * 2 + 1];
    const float4 t0 = reinterpret_cast<const float4*>(sh)[g * 2 + 0];
    const float4 t1 = reinterpret_cast<const float4*>(sh)[g * 2 + 1];
    float ss[8] = {s0.x, s0.y, s0.z, s0.w, s1.x, s1.y, s1.z, s1.w};
    float tt[8] = {t0.x, t0.y, t0.z, t0.w, t1.x, t1.y, t1.z, t1.w};
    short8 v = reinterpret_cast<const short8*>(X)[i];
    float out[8];
#pragma unroll
    for (int j = 0; j < 8; j++) {
        float x = fmaf(b2f_s(v[j]), ss[j], tt[j]);
        out[j] = x > 0.f ? x : a * x;
    }
    float4 o0 = {out[0], out[1], out[2], out[3]};
    float4 o1 = {out[4], out[5], out[6], out[7]};
    reinterpret_cast<float4*>(Y)[i * 2 + 0] = o0;
    reinterpret_cast<float4*>(Y)[i * 2 + 1] = o1;
}

extern "C" void kernel_launch(void* const* d_in, const int* in_sizes, int n_in,
                              void* d_out, int out_size, void* d_ws, size_t ws_size,
                              hipStream_t stream) {
    (void)n_in; (void)out_size; (void)ws_size;
    const float* x   = (const float*)d_in[0];
    const int*   ei  = (const int*)d_in[1];
    const float* W1  = (const float*)d_in[2];
    const float* b1  = (const float*)d_in[3];
    const float* g1  = (const float*)d_in[4];
    const float* be1 = (const float*)d_in[5];
    const float* W2  = (const float*)d_in[6];
    const float* b2  = (const float*)d_in[7];
    const float* g2  = (const float*)d_in[8];
    const float* be2 = (const float*)d_in[9];
    const float* ap  = (const float*)d_in[10];
    float* out = (float*)d_out;

    const int N = in_sizes[0] / 128;
    const int E = in_sizes[1] / 2;
    const int* srcIdx = ei;        // edge_index[0]
    const int* dstIdx = ei + E;    // edge_index[1]

    // ---- workspace layout ----
    char* w = (char*)d_ws;
    size_t off = 0;
    auto alloc = [&](size_t bytes) { char* p = w + off; off += (bytes + 255) & ~(size_t)255; return p; };
    int*   cnt     = (int*)  alloc((size_t)N * 4);
    int*   fillc   = (int*)  alloc((size_t)N * 4);
    int*   rowptr  = (int*)  alloc((size_t)N * 4);
    int*   colw    = (int*)  alloc((size_t)E * 4);
    float* dis     = (float*)alloc((size_t)N * 4);
    int*   partial = (int*)  alloc(4096);
    float* stats1  = (float*)alloc(1024);
    float* stats2  = (float*)alloc(1024);
    float* sc1     = (float*)alloc(512);
    float* sh1     = (float*)alloc(512);
    float* sc2     = (float*)alloc(512);
    float* sh2     = (float*)alloc(512);
    unsigned short* Wz1 = (unsigned short*)alloc(16384 * 2);
    unsigned short* Wz2 = (unsigned short*)alloc(16384 * 2);
    unsigned short* bufX = (unsigned short*)alloc((size_t)N * 128 * 2);   // xb / agg1-out / gemm2-out
    unsigned short* bufH = (unsigned short*)alloc((size_t)N * 128 * 2);   // gemm1-out / act1-out / agg2-out

    const float invN = 1.0f / (float)N;
    const int NB = (N + 1023) / 1024;
    const int gE = (E + 255) / 256;
    const int gN = (N + 255) / 256;
    const int n4 = N * 32;    // float4 groups in x
    const int n8 = N * 16;    // short8 groups per buffer
    const int gGemm = (N + 63) / 64;
    const int gAgg  = (N + 15) / 16;

    hipMemsetAsync(cnt, 0, (size_t)N * 4, stream);
    hipMemsetAsync(fillc, 0, (size_t)N * 4, stream);
    hipMemsetAsync(stats1, 0, 1024, stream);
    hipMemsetAsync(stats2, 0, 1024, stream);

    // casts / weight prep
    k_cast<<<(n4 + 255) / 256, 256, 0, stream>>>(x, bufX, n4);
    k_wprep<<<64, 256, 0, stream>>>(W1, Wz1);
    k_wprep<<<64, 256, 0, stream>>>(W2, Wz2);

    // degree + CSR
    k_count<<<gE, 256, 0, stream>>>(dstIdx, cnt, E);
    k_scanA<<<NB, 256, 0, stream>>>(cnt, partial, N);
    k_scanB<<<1, 128, 0, stream>>>(partial, NB);
    k_scanC<<<NB, 256, 0, stream>>>(cnt, partial, rowptr, N);
    k_dis<<<gN, 256, 0, stream>>>(cnt, dis, N);
    k_fill<<<gE, 256, 0, stream>>>(srcIdx, dstIdx, rowptr, fillc, colw, E);

    // ---- layer 1 ----
    k_gemm_mfma<<<gGemm, 256, 0, stream>>>(bufX, Wz1, bufH, N);                    // h1(bf16) -> bufH
    k_agg<<<gAgg, 256, 0, stream>>>(bufH, rowptr, cnt, colw, dis, b1, bufX, N);    // agg1 -> bufX
    k_bnstats<<<512, 128, 0, stream>>>(bufX, stats1, N);
    k_bnparams<<<1, 128, 0, stream>>>(stats1, g1, be1, sc1, sh1, invN);
    k_bnact_b<<<(n8 + 255) / 256, 256, 0, stream>>>(bufX, bufH, sc1, sh1, ap, n8); // act1 -> bufH

    // ---- layer 2 ----
    k_gemm_mfma<<<gGemm, 256, 0, stream>>>(bufH, Wz2, bufX, N);                    // h2(bf16) -> bufX
    k_agg<<<gAgg, 256, 0, stream>>>(bufX, rowptr, cnt, colw, dis, b2, bufH, N);    // agg2 -> bufH
    k_bnstats<<<512, 128, 0, stream>>>(bufH, stats2, N);
    k_bnparams<<<1, 128, 0, stream>>>(stats2, g2, be2, sc2, sh2, invN);
    k_bnact_f<<<(n8 + 255) / 256, 256, 0, stream>>>(bufH, out, sc2, sh2, ap, n8);  // -> d_out fp32
}